// Round 13
// baseline (899.981 us; speedup 1.0000x reference)
//
#include <hip/hip_runtime.h>
#include <hip/hip_bf16.h>

typedef __attribute__((ext_vector_type(8))) __bf16 bf16x8;
typedef __attribute__((ext_vector_type(4))) float f32x4;
typedef __hip_bfloat16 bf16;

#define SCALE_Q 0.17677669529663687f

// global_load_lds: LDS dest linear (wave-uniform base + lane*16), source pre-swizzled per-lane.
#define LDSP(p) ((__attribute__((address_space(3))) unsigned int*)(unsigned long long)(p))
#define GPTR(p) ((const __attribute__((address_space(1))) unsigned int*)(unsigned long long)(p))
#define GLD16(gp, lp) __builtin_amdgcn_global_load_lds(GPTR(gp), LDSP(lp), 16, 0, 0)

// exact-grade GELU: Abramowitz-Stegun 7.1.26 erf (|err| < 1.5e-7)
__device__ inline float gelu_f(float x) {
  const float ax = fabsf(x) * 0.70710678118654752f;
  const float t = __builtin_amdgcn_rcpf(__builtin_fmaf(0.3275911f, ax, 1.0f));
  const float poly = t * __builtin_fmaf(t, __builtin_fmaf(t, __builtin_fmaf(t,
                     __builtin_fmaf(t, 1.061405429f, -1.453152027f),
                     1.421413741f), -0.284496736f), 0.254829592f);
  const float er = __builtin_fmaf(-poly, __expf(-ax * ax), 1.0f);
  return 0.5f * x * (1.0f + copysignf(er, x));
}

// ---------------- weight fp32 -> bf16 ----------------
__global__ void cvt_kernel(const float* __restrict__ in, bf16* __restrict__ out, int n) {
  int i = blockIdx.x * 256 + threadIdx.x;
  if (i < n) out[i] = __float2bfloat16(in[i]);
}

// ---- weight fp32 -> bf16 in MFMA B-fragment order ----
// src [N][K] row-major; dst chunk (n>>4, k>>5) holds [lg=(k>>3)&3][lr=n&15][e=k&7].
// Wave load for (c16,kc): base + (c16*KC+kc)*512 + lane*8 -> 1KB fully coalesced.
template<int K, int KC>
__global__ void cvt_frag_kernel(const float* __restrict__ in, bf16* __restrict__ out, int total) {
  int i = blockIdx.x * 256 + threadIdx.x;
  if (i < total) {
    const int n = i / K, k = i - n * K;
    out[((n >> 4) * KC + (k >> 5)) * 512 + ((k >> 3) & 3) * 128 + (n & 15) * 8 + (k & 7)] =
        __float2bfloat16(in[i]);
  }
}

// ---- LayerNorm (optionally fused shifted-window gather), fp32 in -> bf16 out ----
template<bool GATHER>
__global__ __launch_bounds__(256) void ln_kernel(const float* __restrict__ in,
                                                 const float* __restrict__ gw,
                                                 const float* __restrict__ gb,
                                                 bf16* __restrict__ out) {
  const int t = blockIdx.x * 4 + (threadIdx.x >> 6);
  const int lane = threadIdx.x & 63;
  long g;
  if (GATHER) {
    const int b_ = t >> 6, n = t & 63;
    const int b = b_ >> 10, wk = b_ & 1023, wi = wk >> 5, wj = wk & 31;
    const int i_ = n >> 3, j_ = n & 7;
    const int hf = (wi * 8 + i_ + 4) & 255, wf = (wj * 8 + j_ + 4) & 255;
    g = (((long)b * 256 + hf) * 256 + wf) * 192;
  } else {
    g = (long)t * 192;
  }
  const float x0 = in[g + lane], x1 = in[g + 64 + lane], x2 = in[g + 128 + lane];
  float s = x0 + x1 + x2;
  float s2 = x0 * x0 + x1 * x1 + x2 * x2;
  #pragma unroll
  for (int m = 1; m < 64; m <<= 1) { s += __shfl_xor(s, m); s2 += __shfl_xor(s2, m); }
  const float mu = s * (1.0f / 192.0f);
  const float rstd = rsqrtf(s2 * (1.0f / 192.0f) - mu * mu + 1e-5f);
  const long o = (long)t * 192;
  out[o + lane]       = __float2bfloat16((x0 - mu) * rstd * gw[lane]       + gb[lane]);
  out[o + 64 + lane]  = __float2bfloat16((x1 - mu) * rstd * gw[lane + 64]  + gb[lane + 64]);
  out[o + 128 + lane] = __float2bfloat16((x2 - mu) * rstd * gw[lane + 128] + gb[lane + 128]);
}

// ---------------- GEMM: C[m][n] = sum_k A[m][k] * W[n][k] (+bias), bf16 MFMA ----------------
// BM=128 BN=192 BK=64, 512 threads (8 waves, 4x2 grid, wave tile 32x96).
// EPI 0: qkv scatter (+q scale)   EPI 1: proj + window-reverse+roll + residual -> h_buf f32
template<int EPI>
__global__ __launch_bounds__(512, 4) void gemm_bt(const bf16* __restrict__ A,
                                                  const bf16* __restrict__ Bw,
                                                  const float* __restrict__ bias,
                                                  int K, void* __restrict__ outp,
                                                  const float* __restrict__ aux1,
                                                  const float* __restrict__ aux2) {
  __shared__ __align__(16) bf16 Ald[128 * 64];
  __shared__ __align__(16) bf16 Bld[192 * 64];
  const int tid = threadIdx.x;
  const int n0 = blockIdx.x * 192;
  const long m0 = (long)blockIdx.y * 128;
  const int lane = tid & 63, wid = tid >> 6;
  const int wr = (wid >> 1) * 32, wc = (wid & 1) * 96;
  const int lg = lane >> 4, lr = lane & 15;
  const int l3 = lane >> 3, l7 = lane & 7;
  const int chunk = l7 ^ l3;  // involutive source swizzle

  const bf16* aptr = A + (m0 + wid * 16 + l3) * (long)K + chunk * 8;
  const bf16* bptr = Bw + (n0 + wid * 24 + l3) * (long)K + chunk * 8;
  char* alds = (char*)Ald + wid * 16 * 128;
  char* blds = (char*)Bld + wid * 24 * 128;
  const long rk8 = 8 * (long)K;

  f32x4 acc[2][6];
  #pragma unroll
  for (int i = 0; i < 2; i++)
    #pragma unroll
    for (int j = 0; j < 6; j++) acc[i][j] = (f32x4){0.f, 0.f, 0.f, 0.f};

  for (int k0 = 0; k0 < K; k0 += 64) {
    GLD16(aptr + k0, alds);
    GLD16(aptr + rk8 + k0, alds + 1024);
    GLD16(bptr + k0, blds);
    GLD16(bptr + rk8 + k0, blds + 1024);
    GLD16(bptr + 2 * rk8 + k0, blds + 2048);
    __syncthreads();
    #pragma unroll
    for (int ks = 0; ks < 2; ks++) {
      bf16x8 af[2], bfr[6];
      #pragma unroll
      for (int i = 0; i < 2; i++) {
        const int row = wr + i * 16 + lr;
        af[i] = *(const bf16x8*)((const char*)Ald + row * 128 + (((ks * 4 + lg) ^ (row & 7)) * 16));
      }
      #pragma unroll
      for (int j = 0; j < 6; j++) {
        const int row = wc + j * 16 + lr;
        bfr[j] = *(const bf16x8*)((const char*)Bld + row * 128 + (((ks * 4 + lg) ^ (row & 7)) * 16));
      }
      #pragma unroll
      for (int i = 0; i < 2; i++)
        #pragma unroll
        for (int j = 0; j < 6; j++)
          acc[i][j] = __builtin_amdgcn_mfma_f32_16x16x32_bf16(af[i], bfr[j], acc[i][j], 0, 0, 0);
    }
    __syncthreads();
  }

  #pragma unroll
  for (int i = 0; i < 2; i++) {
    #pragma unroll
    for (int j = 0; j < 6; j++) {
      #pragma unroll
      for (int r = 0; r < 4; r++) {
        const long m = m0 + wr + i * 16 + lg * 4 + r;   // token row
        const int cn = n0 + wc + j * 16 + lr;           // output col
        float v = acc[i][j][r] + bias[cn];
        if (EPI == 0) {
          const long b_ = m >> 6; const int n = (int)(m & 63);
          const int which = cn / 192, rem = cn - which * 192, head = rem >> 5, d = rem & 31;
          if (which == 0) v *= SCALE_Q;
          ((bf16*)outp)[((b_ * 6 + head) * 3 + which) * 2048 + n * 32 + d] = __float2bfloat16(v);
        } else {
          const long b_ = m >> 6; const int n = (int)(m & 63);
          const int b = (int)(b_ >> 10), wk = (int)(b_ & 1023), wi = wk >> 5, wj = wk & 31;
          const int i_ = n >> 3, j_ = n & 7;
          const int hf = (wi * 8 + i_ + 4) & 255, wf = (wj * 8 + j_ + 4) & 255;
          const long g = (((long)b * 256 + hf) * 256 + wf) * 192 + cn;
          ((float*)outp)[g] = aux1[g] + v;   // h = shortcut + proj(attn)
        }
      }
    }
  }
}

// ---------------- fused MLP v4: out = h + fc2(gelu(fc1(h_ln))) ----------------
// = v3 (BM=32, 512 thr, 60KB LDS, 2 blocks/CU, 2 barriers, fragment-order weights) with
// the fc2 k-loop FULLY UNROLLED + 1-deep B-fragment prefetch. v3's runtime kt-loop
// serialized {addr VALU -> 3 L2 loads -> MFMA} per iteration (MfmaUtil 16%, VALU 42%);
// unrolling folds the swizzle addressing into immediates and lets loads pipeline.
// Accumulation order unchanged -> bitwise-identical results.
__global__ __launch_bounds__(512, 4) void mlp_fused(const bf16* __restrict__ hln,
                                                    const bf16* __restrict__ w1t,
                                                    const float* __restrict__ b1,
                                                    const bf16* __restrict__ w2t,
                                                    const float* __restrict__ b2,
                                                    const float* __restrict__ hbuf,
                                                    float* __restrict__ outp) {
  __shared__ __align__(16) char smem[61440];
  char* Ab = smem;          // hln tile: 3 groups x [32 rows][8 slots][16B] = 12288
  char* G  = smem + 12288;  // g tile: [32 rows][96 slots][16B] = 49152

  const int tid = threadIdx.x;
  const long m0 = (long)blockIdx.x * 32;
  const int lane = tid & 63, wid = tid >> 6;
  const int lg = lane >> 4, lr = lane & 15;

  // ---- stage hln tile once (XOR-swizzled; proven v2 code) ----
  {
    const int f = wid * 64 + lane;
    const int row = (f >> 3) & 31, q = f >> 8, slot = f & 7;
    const int c = slot ^ (row & 7);
    GLD16(hln + (m0 + row) * 192 + (q * 8 + c) * 8, Ab + wid * 1024 + lane * 16);
    if (wid < 4) {
      const int f2 = 512 + wid * 64 + lane;
      const int row2 = (f2 >> 3) & 31, q2 = f2 >> 8, slot2 = f2 & 7;
      const int c2 = slot2 ^ (row2 & 7);
      GLD16(hln + (m0 + row2) * 192 + (q2 * 8 + c2) * 8, Ab + 8192 + wid * 1024 + lane * 16);
    }
  }
  __syncthreads();

  // ---------------- fc1: barrier-free k-loop (A from LDS, w1t fragments from L2) ----------------
  f32x4 acc1[2][6];
  #pragma unroll
  for (int i = 0; i < 2; i++)
    #pragma unroll
    for (int j = 0; j < 6; j++) acc1[i][j] = (f32x4){0.f, 0.f, 0.f, 0.f};

  const int c16base = wid * 6;  // wave cols = wid*96 .. +96
  #pragma unroll
  for (int kc = 0; kc < 6; kc++) {
    const int q = kc >> 1;
    const int kk = (kc & 1) * 4 + lg;
    bf16x8 af[2], bfr[6];
    #pragma unroll
    for (int i = 0; i < 2; i++) {
      const int row = i * 16 + lr;
      af[i] = *(const bf16x8*)(Ab + q * 4096 + row * 128 + ((kk ^ (row & 7)) * 16));
    }
    #pragma unroll
    for (int j = 0; j < 6; j++)
      bfr[j] = *(const bf16x8*)(w1t + ((c16base + j) * 6 + kc) * 512 + lane * 8);
    #pragma unroll
    for (int i = 0; i < 2; i++)
      #pragma unroll
      for (int j = 0; j < 6; j++)
        acc1[i][j] = __builtin_amdgcn_mfma_f32_16x16x32_bf16(af[i], bfr[j], acc1[i][j], 0, 0, 0);
  }

  // gelu + write g tile to LDS (XOR-swizzled; proven v2 code)
  #pragma unroll
  for (int j = 0; j < 6; j++) {
    const int n = wid * 96 + j * 16 + lr;
    const float bj = b1[n];
    const int c = n >> 3;
    #pragma unroll
    for (int i = 0; i < 2; i++) {
      #pragma unroll
      for (int r = 0; r < 4; r++) {
        const int m = i * 16 + lg * 4 + r;
        const int slot = (c & ~7) | ((c & 7) ^ (m & 7));
        *(unsigned short*)(G + m * 1536 + slot * 16 + (n & 7) * 2) =
            __builtin_bit_cast(unsigned short, __float2bfloat16(gelu_f(acc1[i][j][r] + bj)));
      }
    }
  }
  __syncthreads();

  // ------- fc2: fully-unrolled, 1-deep prefetched k-loop (A from LDS g, w2t from L2) -------
  const int wt = wid >> 2, wn = wid & 3;
  f32x4 acc2[3];
  #pragma unroll
  for (int j = 0; j < 3; j++) acc2[j] = (f32x4){0.f, 0.f, 0.f, 0.f};

  const int grow = wt * 16 + lr;
  const bf16* w2base = w2t + (wn * 3 * 24) * 512 + lane * 8;

  bf16x8 nb[3];
  #pragma unroll
  for (int j = 0; j < 3; j++) nb[j] = *(const bf16x8*)(w2base + (j * 24) * 512);

  #pragma unroll
  for (int kt = 0; kt < 24; kt++) {
    bf16x8 cb[3];
    #pragma unroll
    for (int j = 0; j < 3; j++) cb[j] = nb[j];
    if (kt < 23) {
      #pragma unroll
      for (int j = 0; j < 3; j++)
        nb[j] = *(const bf16x8*)(w2base + (j * 24 + kt + 1) * 512);
    }
    const int c2 = kt * 4 + lg;  // global g chunk 0..95
    const int slot2 = (c2 & ~7) | ((c2 & 7) ^ (grow & 7));
    const bf16x8 af2 = *(const bf16x8*)(G + grow * 1536 + slot2 * 16);
    #pragma unroll
    for (int j = 0; j < 3; j++)
      acc2[j] = __builtin_amdgcn_mfma_f32_16x16x32_bf16(af2, cb[j], acc2[j], 0, 0, 0);
  }

  // epilogue: + bias + residual h -> out (f32)
  #pragma unroll
  for (int j = 0; j < 3; j++) {
    const int cn = wn * 48 + j * 16 + lr;
    const float bj = b2[cn];
    #pragma unroll
    for (int r = 0; r < 4; r++) {
      const long m = m0 + wt * 16 + lg * 4 + r;
      outp[m * 192 + cn] = acc2[j][r] + bj + hbuf[m * 192 + cn];
    }
  }
}

// ---------------- windowed attention: one wave per (window, head) — proven round-1 ----------------
__global__ __launch_bounds__(64) void attn_kernel(const bf16* __restrict__ qkv,
                                                  const float* __restrict__ rpb,
                                                  bf16* __restrict__ outp) {
  __shared__ __align__(16) char smem[14848];
  __shared__ float rps[225];
  const int bid = blockIdx.x;
  const int b_ = bid / 6, head = bid - b_ * 6;
  const int lane = threadIdx.x;
  const long base = ((long)b_ * 6 + head) * 3 * 2048;

  for (int t = lane; t < 225; t += 64) rps[t] = rpb[t * 6 + head];

  #pragma unroll
  for (int q = 0; q < 4; q++) {
    const int f = q * 64 + lane, row = f >> 2, c = f & 3;
    *(uint4*)(smem + row * 80 + c * 16) = *(const uint4*)(qkv + base + row * 32 + c * 8);
    *(uint4*)(smem + 5120 + row * 80 + c * 16) = *(const uint4*)(qkv + base + 2048 + row * 32 + c * 8);
  }
  {  // stage V transposed: Vt[d][m]
    const bf16* vsrc = qkv + base + 4096 + lane * 32;
    bf16 vv[32];
    #pragma unroll
    for (int q = 0; q < 4; q++) *(uint4*)&vv[q * 8] = *(const uint4*)(vsrc + q * 8);
    bf16* vt = (bf16*)(smem + 10240);
    #pragma unroll
    for (int d = 0; d < 32; d++) vt[d * 72 + lane] = vv[d];
  }
  __syncthreads();

  const int lg = lane >> 4, lr = lane & 15;
  const f32x4 z4 = {0.f, 0.f, 0.f, 0.f};
  f32x4 s[4][4];
  {
    bf16x8 a[4], b[4];
    #pragma unroll
    for (int fi = 0; fi < 4; fi++)
      a[fi] = *(const bf16x8*)(smem + (fi * 16 + lr) * 80 + lg * 16);
    #pragma unroll
    for (int fj = 0; fj < 4; fj++)
      b[fj] = *(const bf16x8*)(smem + 5120 + (fj * 16 + lr) * 80 + lg * 16);
    #pragma unroll
    for (int fi = 0; fi < 4; fi++)
      #pragma unroll
      for (int fj = 0; fj < 4; fj++)
        s[fi][fj] = __builtin_amdgcn_mfma_f32_16x16x32_bf16(a[fi], b[fj], z4, 0, 0, 0);
  }

  const int wk = b_ & 1023; const int wi = wk >> 5, wj = wk & 31;
  const bool eh = (wi == 31), ew = (wj == 31);
  bf16* P = (bf16*)smem;
  #pragma unroll
  for (int fi = 0; fi < 4; fi++) {
    #pragma unroll
    for (int r = 0; r < 4; r++) {
      const int n = fi * 16 + lg * 4 + r;
      const int i1 = n >> 3, j1 = n & 7;
      const int labn = (eh ? (i1 < 4 ? 3 : 6) : 0) + (ew ? (j1 < 4 ? 1 : 2) : 0);
      float vals[4];
      #pragma unroll
      for (int fj = 0; fj < 4; fj++) {
        const int m = fj * 16 + lr;
        const int i2 = m >> 3, j2 = m & 7;
        const int labm = (eh ? (i2 < 4 ? 3 : 6) : 0) + (ew ? (j2 < 4 ? 1 : 2) : 0);
        vals[fj] = s[fi][fj][r] + rps[(i1 - i2 + 7) * 15 + (j1 - j2 + 7)]
                 + (labn != labm ? -100.0f : 0.0f);
      }
      float mx = fmaxf(fmaxf(vals[0], vals[1]), fmaxf(vals[2], vals[3]));
      #pragma unroll
      for (int msk = 1; msk < 16; msk <<= 1) mx = fmaxf(mx, __shfl_xor(mx, msk));
      float pe[4]; float sum = 0.f;
      #pragma unroll
      for (int fj = 0; fj < 4; fj++) { pe[fj] = __expf(vals[fj] - mx); sum += pe[fj]; }
      #pragma unroll
      for (int msk = 1; msk < 16; msk <<= 1) sum += __shfl_xor(sum, msk);
      const float rinv = 1.0f / sum;
      #pragma unroll
      for (int fj = 0; fj < 4; fj++)
        P[n * 72 + fj * 16 + lr] = __float2bfloat16(pe[fj] * rinv);
    }
  }
  __syncthreads();

  f32x4 o[4][2];
  #pragma unroll
  for (int fi = 0; fi < 4; fi++)
    #pragma unroll
    for (int fd = 0; fd < 2; fd++) o[fi][fd] = z4;
  const bf16* vt = (const bf16*)(smem + 10240);
  #pragma unroll
  for (int ks = 0; ks < 2; ks++) {
    bf16x8 pa[4], vb[2];
    #pragma unroll
    for (int fi = 0; fi < 4; fi++)
      pa[fi] = *(const bf16x8*)(P + (fi * 16 + lr) * 72 + ks * 32 + lg * 8);
    #pragma unroll
    for (int fd = 0; fd < 2; fd++)
      vb[fd] = *(const bf16x8*)(vt + (fd * 16 + lr) * 72 + ks * 32 + lg * 8);
    #pragma unroll
    for (int fi = 0; fi < 4; fi++)
      #pragma unroll
      for (int fd = 0; fd < 2; fd++)
        o[fi][fd] = __builtin_amdgcn_mfma_f32_16x16x32_bf16(pa[fi], vb[fd], o[fi][fd], 0, 0, 0);
  }
  #pragma unroll
  for (int fi = 0; fi < 4; fi++)
    #pragma unroll
    for (int fd = 0; fd < 2; fd++)
      #pragma unroll
      for (int r = 0; r < 4; r++) {
        const int n = fi * 16 + lg * 4 + r;
        outp[((long)b_ * 64 + n) * 192 + head * 32 + fd * 16 + lr] = __float2bfloat16(o[fi][fd][r]);
      }
}

extern "C" void kernel_launch(void* const* d_in, const int* in_sizes, int n_in,
                              void* d_out, int out_size, void* d_ws, size_t ws_size,
                              hipStream_t stream) {
  const float* x      = (const float*)d_in[0];
  const float* qkv_w  = (const float*)d_in[1];
  const float* qkv_b  = (const float*)d_in[2];
  const float* proj_w = (const float*)d_in[3];
  const float* proj_b = (const float*)d_in[4];
  const float* rpb    = (const float*)d_in[5];
  const float* n1_w   = (const float*)d_in[6];
  const float* n1_b   = (const float*)d_in[7];
  const float* n2_w   = (const float*)d_in[8];
  const float* n2_b   = (const float*)d_in[9];
  const float* fc1_w  = (const float*)d_in[10];
  const float* fc1_b  = (const float*)d_in[11];
  const float* fc2_w  = (const float*)d_in[12];
  const float* fc2_b  = (const float*)d_in[13];

  char* ws = (char*)d_ws;
  // workspace layout — round-1/5 proven layout (g region unused):
  // [0, 884736)             weights bf16 (fc1/fc2 in fragment order)
  // [1 MiB, +100663296)     R1: zw -> attn_out -> h_ln  (bf16, M x 192)
  // [101711872, +402653184) R2: qkv (M x 576)  (bf16)
  // [504365056, +201326592) R3: h_buf (M x 192 f32, original token order)
  bf16* qkvw_h  = (bf16*)(ws);
  bf16* projw_h = (bf16*)(ws + 221184);
  bf16* fc1w_t  = (bf16*)(ws + 294912);
  bf16* fc2w_t  = (bf16*)(ws + 589824);
  bf16* r1      = (bf16*)(ws + (1L << 20));
  bf16* r2      = (bf16*)(ws + 101711872L);
  float* hbuf   = (float*)(ws + 504365056L);

  cvt_kernel<<<432, 256, 0, stream>>>(qkv_w, qkvw_h, 110592);
  cvt_kernel<<<144, 256, 0, stream>>>(proj_w, projw_h, 36864);
  cvt_frag_kernel<192, 6><<<576, 256, 0, stream>>>(fc1_w, fc1w_t, 147456);
  cvt_frag_kernel<768, 24><<<576, 256, 0, stream>>>(fc2_w, fc2w_t, 147456);

  // LN1 + roll + window partition -> zw (r1)
  ln_kernel<true><<<65536, 256, 0, stream>>>(x, n1_w, n1_b, r1);
  // QKV: zw @ qkv_w^T -> per-(window,head) Q|K|V blocks (r2)
  gemm_bt<0><<<dim3(3, 2048), 512, 0, stream>>>(r1, qkvw_h, qkv_b, 192, r2, nullptr, nullptr);
  // windowed attention -> attn_out (r1)
  attn_kernel<<<24576, 64, 0, stream>>>(r2, rpb, r1);
  // proj + window-reverse + roll + residual -> h_buf (r3, original order)
  gemm_bt<1><<<dim3(1, 2048), 512, 0, stream>>>(r1, projw_h, proj_b, 192, hbuf, x, nullptr);
  // LN2 -> h_ln (r1)
  ln_kernel<false><<<65536, 256, 0, stream>>>(hbuf, n2_w, n2_b, r1);
  // fused MLP: out = h + fc2(gelu(fc1(h_ln)))
  mlp_fused<<<8192, 512, 0, stream>>>(r1, fc1w_t, fc1_b, fc2w_t, fc2_b, hbuf, (float*)d_out);
}

// Round 14
// 819.511 us; speedup vs baseline: 1.0982x; 1.0982x over previous
//
#include <hip/hip_runtime.h>
#include <hip/hip_bf16.h>

typedef __attribute__((ext_vector_type(8))) __bf16 bf16x8;
typedef __attribute__((ext_vector_type(4))) float f32x4;
typedef __hip_bfloat16 bf16;

#define SCALE_Q 0.17677669529663687f

// global_load_lds: LDS dest linear (wave-uniform base + lane*16), source pre-swizzled per-lane.
#define LDSP(p) ((__attribute__((address_space(3))) unsigned int*)(unsigned long long)(p))
#define GPTR(p) ((const __attribute__((address_space(1))) unsigned int*)(unsigned long long)(p))
#define GLD16(gp, lp) __builtin_amdgcn_global_load_lds(GPTR(gp), LDSP(lp), 16, 0, 0)

// exact-grade GELU: Abramowitz-Stegun 7.1.26 erf (|err| < 1.5e-7)
__device__ inline float gelu_f(float x) {
  const float ax = fabsf(x) * 0.70710678118654752f;
  const float t = __builtin_amdgcn_rcpf(__builtin_fmaf(0.3275911f, ax, 1.0f));
  const float poly = t * __builtin_fmaf(t, __builtin_fmaf(t, __builtin_fmaf(t,
                     __builtin_fmaf(t, 1.061405429f, -1.453152027f),
                     1.421413741f), -0.284496736f), 0.254829592f);
  const float er = __builtin_fmaf(-poly, __expf(-ax * ax), 1.0f);
  return 0.5f * x * (1.0f + copysignf(er, x));
}

// ---------------- weight fp32 -> bf16 ----------------
__global__ void cvt_kernel(const float* __restrict__ in, bf16* __restrict__ out, int n) {
  int i = blockIdx.x * 256 + threadIdx.x;
  if (i < n) out[i] = __float2bfloat16(in[i]);
}

// ---- weight fp32 -> bf16 in MFMA B-fragment order ----
// src [N][K] row-major; dst chunk (n>>4, k>>5) holds [lg=(k>>3)&3][lr=n&15][e=k&7].
template<int K, int KC>
__global__ void cvt_frag_kernel(const float* __restrict__ in, bf16* __restrict__ out, int total) {
  int i = blockIdx.x * 256 + threadIdx.x;
  if (i < total) {
    const int n = i / K, k = i - n * K;
    out[((n >> 4) * KC + (k >> 5)) * 512 + ((k >> 3) & 3) * 128 + (n & 15) * 8 + (k & 7)] =
        __float2bfloat16(in[i]);
  }
}

// ---- LayerNorm1 fused with shifted-window gather, fp32 in -> bf16 out ----
__global__ __launch_bounds__(256) void ln_kernel(const float* __restrict__ in,
                                                 const float* __restrict__ gw,
                                                 const float* __restrict__ gb,
                                                 bf16* __restrict__ out) {
  const int t = blockIdx.x * 4 + (threadIdx.x >> 6);
  const int lane = threadIdx.x & 63;
  const int b_ = t >> 6, n = t & 63;
  const int b = b_ >> 10, wk = b_ & 1023, wi = wk >> 5, wj = wk & 31;
  const int i_ = n >> 3, j_ = n & 7;
  const int hf = (wi * 8 + i_ + 4) & 255, wf = (wj * 8 + j_ + 4) & 255;
  const long g = (((long)b * 256 + hf) * 256 + wf) * 192;
  const float x0 = in[g + lane], x1 = in[g + 64 + lane], x2 = in[g + 128 + lane];
  float s = x0 + x1 + x2;
  float s2 = x0 * x0 + x1 * x1 + x2 * x2;
  #pragma unroll
  for (int m = 1; m < 64; m <<= 1) { s += __shfl_xor(s, m); s2 += __shfl_xor(s2, m); }
  const float mu = s * (1.0f / 192.0f);
  const float rstd = rsqrtf(s2 * (1.0f / 192.0f) - mu * mu + 1e-5f);
  const long o = (long)t * 192;
  out[o + lane]       = __float2bfloat16((x0 - mu) * rstd * gw[lane]       + gb[lane]);
  out[o + 64 + lane]  = __float2bfloat16((x1 - mu) * rstd * gw[lane + 64]  + gb[lane + 64]);
  out[o + 128 + lane] = __float2bfloat16((x2 - mu) * rstd * gw[lane + 128] + gb[lane + 128]);
}

// ---------------- GEMM: C[m][n] = sum_k A[m][k] * W[n][k] (+bias), bf16 MFMA ----------------
// BM=128 BN=192 BK=64, 512 threads (8 waves, 4x2 grid, wave tile 32x96).
// EPI 0: qkv scatter (+q scale)   EPI 1: proj + window-reverse+roll + residual -> h_buf f32
template<int EPI>
__global__ __launch_bounds__(512, 4) void gemm_bt(const bf16* __restrict__ A,
                                                  const bf16* __restrict__ Bw,
                                                  const float* __restrict__ bias,
                                                  int K, void* __restrict__ outp,
                                                  const float* __restrict__ aux1,
                                                  const float* __restrict__ aux2) {
  __shared__ __align__(16) bf16 Ald[128 * 64];
  __shared__ __align__(16) bf16 Bld[192 * 64];
  const int tid = threadIdx.x;
  const int n0 = blockIdx.x * 192;
  const long m0 = (long)blockIdx.y * 128;
  const int lane = tid & 63, wid = tid >> 6;
  const int wr = (wid >> 1) * 32, wc = (wid & 1) * 96;
  const int lg = lane >> 4, lr = lane & 15;
  const int l3 = lane >> 3, l7 = lane & 7;
  const int chunk = l7 ^ l3;  // involutive source swizzle

  const bf16* aptr = A + (m0 + wid * 16 + l3) * (long)K + chunk * 8;
  const bf16* bptr = Bw + (n0 + wid * 24 + l3) * (long)K + chunk * 8;
  char* alds = (char*)Ald + wid * 16 * 128;
  char* blds = (char*)Bld + wid * 24 * 128;
  const long rk8 = 8 * (long)K;

  f32x4 acc[2][6];
  #pragma unroll
  for (int i = 0; i < 2; i++)
    #pragma unroll
    for (int j = 0; j < 6; j++) acc[i][j] = (f32x4){0.f, 0.f, 0.f, 0.f};

  for (int k0 = 0; k0 < K; k0 += 64) {
    GLD16(aptr + k0, alds);
    GLD16(aptr + rk8 + k0, alds + 1024);
    GLD16(bptr + k0, blds);
    GLD16(bptr + rk8 + k0, blds + 1024);
    GLD16(bptr + 2 * rk8 + k0, blds + 2048);
    __syncthreads();
    #pragma unroll
    for (int ks = 0; ks < 2; ks++) {
      bf16x8 af[2], bfr[6];
      #pragma unroll
      for (int i = 0; i < 2; i++) {
        const int row = wr + i * 16 + lr;
        af[i] = *(const bf16x8*)((const char*)Ald + row * 128 + (((ks * 4 + lg) ^ (row & 7)) * 16));
      }
      #pragma unroll
      for (int j = 0; j < 6; j++) {
        const int row = wc + j * 16 + lr;
        bfr[j] = *(const bf16x8*)((const char*)Bld + row * 128 + (((ks * 4 + lg) ^ (row & 7)) * 16));
      }
      #pragma unroll
      for (int i = 0; i < 2; i++)
        #pragma unroll
        for (int j = 0; j < 6; j++)
          acc[i][j] = __builtin_amdgcn_mfma_f32_16x16x32_bf16(af[i], bfr[j], acc[i][j], 0, 0, 0);
    }
    __syncthreads();
  }

  #pragma unroll
  for (int i = 0; i < 2; i++) {
    #pragma unroll
    for (int j = 0; j < 6; j++) {
      #pragma unroll
      for (int r = 0; r < 4; r++) {
        const long m = m0 + wr + i * 16 + lg * 4 + r;   // token row
        const int cn = n0 + wc + j * 16 + lr;           // output col
        float v = acc[i][j][r] + bias[cn];
        if (EPI == 0) {
          const long b_ = m >> 6; const int n = (int)(m & 63);
          const int which = cn / 192, rem = cn - which * 192, head = rem >> 5, d = rem & 31;
          if (which == 0) v *= SCALE_Q;
          ((bf16*)outp)[((b_ * 6 + head) * 3 + which) * 2048 + n * 32 + d] = __float2bfloat16(v);
        } else {
          const long b_ = m >> 6; const int n = (int)(m & 63);
          const int b = (int)(b_ >> 10), wk = (int)(b_ & 1023), wi = wk >> 5, wj = wk & 31;
          const int i_ = n >> 3, j_ = n & 7;
          const int hf = (wi * 8 + i_ + 4) & 255, wf = (wj * 8 + j_ + 4) & 255;
          const long g = (((long)b * 256 + hf) * 256 + wf) * 192 + cn;
          ((float*)outp)[g] = aux1[g] + v;   // h = shortcut + proj(attn)
        }
      }
    }
  }
}

// ------------ fused MLP v5: out = h + fc2(gelu(fc1(LN2(h)))) — LN2 fused in ------------
// = v3 (BM=32, 512 thr, 60KB LDS, 2 blocks/CU, 2 barriers, fragment-order weights,
//   v3's runtime fc2 loop — v4's unroll regressed) with LN2 computed in-kernel:
// each wave LN-normalizes 4 hbuf rows (exact ln_kernel math/order) and writes bf16
// into the swizzled Ab tile (chunk c -> slot c^(row&7), elem ch&7 — bit-identical
// bytes to what GLD16-from-hln produced). Eliminates the ln2 kernel + hln buffer.
__global__ __launch_bounds__(512, 4) void mlp_fused(const float* __restrict__ hbuf,
                                                    const float* __restrict__ n2w,
                                                    const float* __restrict__ n2b,
                                                    const bf16* __restrict__ w1t,
                                                    const float* __restrict__ b1,
                                                    const bf16* __restrict__ w2t,
                                                    const float* __restrict__ b2,
                                                    float* __restrict__ outp) {
  __shared__ __align__(16) char smem[61440];
  char* Ab = smem;          // h_ln tile: 3 groups x [32 rows][8 slots][16B] = 12288
  char* G  = smem + 12288;  // g tile: [32 rows][96 slots][16B] = 49152

  const int tid = threadIdx.x;
  const long m0 = (long)blockIdx.x * 32;
  const int lane = tid & 63, wid = tid >> 6;
  const int lg = lane >> 4, lr = lane & 15;

  // ---- LN2: each wave normalizes 4 rows of hbuf -> Ab (swizzled bf16) ----
  #pragma unroll
  for (int t4 = 0; t4 < 4; t4++) {
    const int row = wid * 4 + t4;
    const long g = (m0 + row) * 192;
    const float x0 = hbuf[g + lane], x1 = hbuf[g + 64 + lane], x2 = hbuf[g + 128 + lane];
    float s = x0 + x1 + x2;
    float s2 = x0 * x0 + x1 * x1 + x2 * x2;
    #pragma unroll
    for (int msk = 1; msk < 64; msk <<= 1) { s += __shfl_xor(s, msk); s2 += __shfl_xor(s2, msk); }
    const float mu = s * (1.0f / 192.0f);
    const float rstd = rsqrtf(s2 * (1.0f / 192.0f) - mu * mu + 1e-5f);
    #pragma unroll
    for (int p = 0; p < 3; p++) {
      const int ch = p * 64 + lane;
      const float xv = (p == 0) ? x0 : (p == 1) ? x1 : x2;
      const float v = (xv - mu) * rstd * n2w[ch] + n2b[ch];
      const int c = (ch >> 3) & 7;               // chunk within 64-ch group
      const int slot = c ^ (row & 7);
      *(unsigned short*)(Ab + p * 4096 + row * 128 + slot * 16 + (ch & 7) * 2) =
          __builtin_bit_cast(unsigned short, __float2bfloat16(v));
    }
  }
  __syncthreads();

  // ---------------- fc1: barrier-free k-loop (A from LDS, w1t fragments from L2) ----------------
  f32x4 acc1[2][6];
  #pragma unroll
  for (int i = 0; i < 2; i++)
    #pragma unroll
    for (int j = 0; j < 6; j++) acc1[i][j] = (f32x4){0.f, 0.f, 0.f, 0.f};

  const int c16base = wid * 6;  // wave cols = wid*96 .. +96
  #pragma unroll
  for (int kc = 0; kc < 6; kc++) {
    const int q = kc >> 1;
    const int kk = (kc & 1) * 4 + lg;
    bf16x8 af[2], bfr[6];
    #pragma unroll
    for (int i = 0; i < 2; i++) {
      const int row = i * 16 + lr;
      af[i] = *(const bf16x8*)(Ab + q * 4096 + row * 128 + ((kk ^ (row & 7)) * 16));
    }
    #pragma unroll
    for (int j = 0; j < 6; j++)
      bfr[j] = *(const bf16x8*)(w1t + ((c16base + j) * 6 + kc) * 512 + lane * 8);
    #pragma unroll
    for (int i = 0; i < 2; i++)
      #pragma unroll
      for (int j = 0; j < 6; j++)
        acc1[i][j] = __builtin_amdgcn_mfma_f32_16x16x32_bf16(af[i], bfr[j], acc1[i][j], 0, 0, 0);
  }

  // gelu + write g tile to LDS (XOR-swizzled; proven v2/v3 code)
  #pragma unroll
  for (int j = 0; j < 6; j++) {
    const int n = wid * 96 + j * 16 + lr;
    const float bj = b1[n];
    const int c = n >> 3;
    #pragma unroll
    for (int i = 0; i < 2; i++) {
      #pragma unroll
      for (int r = 0; r < 4; r++) {
        const int m = i * 16 + lg * 4 + r;
        const int slot = (c & ~7) | ((c & 7) ^ (m & 7));
        *(unsigned short*)(G + m * 1536 + slot * 16 + (n & 7) * 2) =
            __builtin_bit_cast(unsigned short, __float2bfloat16(gelu_f(acc1[i][j][r] + bj)));
      }
    }
  }
  __syncthreads();

  // ---------------- fc2: v3's runtime k-loop (A from LDS g, w2t fragments from L2) ----------------
  const int wt = wid >> 2, wn = wid & 3;
  f32x4 acc2[3];
  #pragma unroll
  for (int j = 0; j < 3; j++) acc2[j] = (f32x4){0.f, 0.f, 0.f, 0.f};

  const int grow = wt * 16 + lr;
  for (int kt = 0; kt < 24; kt++) {
    const int c2 = kt * 4 + lg;  // global g chunk 0..95
    const int slot2 = (c2 & ~7) | ((c2 & 7) ^ (grow & 7));
    const bf16x8 af2 = *(const bf16x8*)(G + grow * 1536 + slot2 * 16);
    bf16x8 bfr2[3];
    #pragma unroll
    for (int j = 0; j < 3; j++)
      bfr2[j] = *(const bf16x8*)(w2t + ((wn * 3 + j) * 24 + kt) * 512 + lane * 8);
    #pragma unroll
    for (int j = 0; j < 3; j++)
      acc2[j] = __builtin_amdgcn_mfma_f32_16x16x32_bf16(af2, bfr2[j], acc2[j], 0, 0, 0);
  }

  // epilogue: + bias + residual h -> out (f32)
  #pragma unroll
  for (int j = 0; j < 3; j++) {
    const int cn = wn * 48 + j * 16 + lr;
    const float bj = b2[cn];
    #pragma unroll
    for (int r = 0; r < 4; r++) {
      const long m = m0 + wt * 16 + lg * 4 + r;
      outp[m * 192 + cn] = acc2[j][r] + bj + hbuf[m * 192 + cn];
    }
  }
}

// ---------------- windowed attention: one wave per (window, head) — proven round-1 ----------------
__global__ __launch_bounds__(64) void attn_kernel(const bf16* __restrict__ qkv,
                                                  const float* __restrict__ rpb,
                                                  bf16* __restrict__ outp) {
  __shared__ __align__(16) char smem[14848];
  __shared__ float rps[225];
  const int bid = blockIdx.x;
  const int b_ = bid / 6, head = bid - b_ * 6;
  const int lane = threadIdx.x;
  const long base = ((long)b_ * 6 + head) * 3 * 2048;

  for (int t = lane; t < 225; t += 64) rps[t] = rpb[t * 6 + head];

  #pragma unroll
  for (int q = 0; q < 4; q++) {
    const int f = q * 64 + lane, row = f >> 2, c = f & 3;
    *(uint4*)(smem + row * 80 + c * 16) = *(const uint4*)(qkv + base + row * 32 + c * 8);
    *(uint4*)(smem + 5120 + row * 80 + c * 16) = *(const uint4*)(qkv + base + 2048 + row * 32 + c * 8);
  }
  {  // stage V transposed: Vt[d][m]
    const bf16* vsrc = qkv + base + 4096 + lane * 32;
    bf16 vv[32];
    #pragma unroll
    for (int q = 0; q < 4; q++) *(uint4*)&vv[q * 8] = *(const uint4*)(vsrc + q * 8);
    bf16* vt = (bf16*)(smem + 10240);
    #pragma unroll
    for (int d = 0; d < 32; d++) vt[d * 72 + lane] = vv[d];
  }
  __syncthreads();

  const int lg = lane >> 4, lr = lane & 15;
  const f32x4 z4 = {0.f, 0.f, 0.f, 0.f};
  f32x4 s[4][4];
  {
    bf16x8 a[4], b[4];
    #pragma unroll
    for (int fi = 0; fi < 4; fi++)
      a[fi] = *(const bf16x8*)(smem + (fi * 16 + lr) * 80 + lg * 16);
    #pragma unroll
    for (int fj = 0; fj < 4; fj++)
      b[fj] = *(const bf16x8*)(smem + 5120 + (fj * 16 + lr) * 80 + lg * 16);
    #pragma unroll
    for (int fi = 0; fi < 4; fi++)
      #pragma unroll
      for (int fj = 0; fj < 4; fj++)
        s[fi][fj] = __builtin_amdgcn_mfma_f32_16x16x32_bf16(a[fi], b[fj], z4, 0, 0, 0);
  }

  const int wk = b_ & 1023; const int wi = wk >> 5, wj = wk & 31;
  const bool eh = (wi == 31), ew = (wj == 31);
  bf16* P = (bf16*)smem;
  #pragma unroll
  for (int fi = 0; fi < 4; fi++) {
    #pragma unroll
    for (int r = 0; r < 4; r++) {
      const int n = fi * 16 + lg * 4 + r;
      const int i1 = n >> 3, j1 = n & 7;
      const int labn = (eh ? (i1 < 4 ? 3 : 6) : 0) + (ew ? (j1 < 4 ? 1 : 2) : 0);
      float vals[4];
      #pragma unroll
      for (int fj = 0; fj < 4; fj++) {
        const int m = fj * 16 + lr;
        const int i2 = m >> 3, j2 = m & 7;
        const int labm = (eh ? (i2 < 4 ? 3 : 6) : 0) + (ew ? (j2 < 4 ? 1 : 2) : 0);
        vals[fj] = s[fi][fj][r] + rps[(i1 - i2 + 7) * 15 + (j1 - j2 + 7)]
                 + (labn != labm ? -100.0f : 0.0f);
      }
      float mx = fmaxf(fmaxf(vals[0], vals[1]), fmaxf(vals[2], vals[3]));
      #pragma unroll
      for (int msk = 1; msk < 16; msk <<= 1) mx = fmaxf(mx, __shfl_xor(mx, msk));
      float pe[4]; float sum = 0.f;
      #pragma unroll
      for (int fj = 0; fj < 4; fj++) { pe[fj] = __expf(vals[fj] - mx); sum += pe[fj]; }
      #pragma unroll
      for (int msk = 1; msk < 16; msk <<= 1) sum += __shfl_xor(sum, msk);
      const float rinv = 1.0f / sum;
      #pragma unroll
      for (int fj = 0; fj < 4; fj++)
        P[n * 72 + fj * 16 + lr] = __float2bfloat16(pe[fj] * rinv);
    }
  }
  __syncthreads();

  f32x4 o[4][2];
  #pragma unroll
  for (int fi = 0; fi < 4; fi++)
    #pragma unroll
    for (int fd = 0; fd < 2; fd++) o[fi][fd] = z4;
  const bf16* vt = (const bf16*)(smem + 10240);
  #pragma unroll
  for (int ks = 0; ks < 2; ks++) {
    bf16x8 pa[4], vb[2];
    #pragma unroll
    for (int fi = 0; fi < 4; fi++)
      pa[fi] = *(const bf16x8*)(P + (fi * 16 + lr) * 72 + ks * 32 + lg * 8);
    #pragma unroll
    for (int fd = 0; fd < 2; fd++)
      vb[fd] = *(const bf16x8*)(vt + (fd * 16 + lr) * 72 + ks * 32 + lg * 8);
    #pragma unroll
    for (int fi = 0; fi < 4; fi++)
      #pragma unroll
      for (int fd = 0; fd < 2; fd++)
        o[fi][fd] = __builtin_amdgcn_mfma_f32_16x16x32_bf16(pa[fi], vb[fd], o[fi][fd], 0, 0, 0);
  }
  #pragma unroll
  for (int fi = 0; fi < 4; fi++)
    #pragma unroll
    for (int fd = 0; fd < 2; fd++)
      #pragma unroll
      for (int r = 0; r < 4; r++) {
        const int n = fi * 16 + lg * 4 + r;
        outp[((long)b_ * 64 + n) * 192 + head * 32 + fd * 16 + lr] = __float2bfloat16(o[fi][fd][r]);
      }
}

extern "C" void kernel_launch(void* const* d_in, const int* in_sizes, int n_in,
                              void* d_out, int out_size, void* d_ws, size_t ws_size,
                              hipStream_t stream) {
  const float* x      = (const float*)d_in[0];
  const float* qkv_w  = (const float*)d_in[1];
  const float* qkv_b  = (const float*)d_in[2];
  const float* proj_w = (const float*)d_in[3];
  const float* proj_b = (const float*)d_in[4];
  const float* rpb    = (const float*)d_in[5];
  const float* n1_w   = (const float*)d_in[6];
  const float* n1_b   = (const float*)d_in[7];
  const float* n2_w   = (const float*)d_in[8];
  const float* n2_b   = (const float*)d_in[9];
  const float* fc1_w  = (const float*)d_in[10];
  const float* fc1_b  = (const float*)d_in[11];
  const float* fc2_w  = (const float*)d_in[12];
  const float* fc2_b  = (const float*)d_in[13];

  char* ws = (char*)d_ws;
  // workspace layout — round-1/5 proven layout (g + hln regions now unused):
  // [0, 884736)             weights bf16 (fc1/fc2 in fragment order)
  // [1 MiB, +100663296)     R1: zw -> attn_out  (bf16, M x 192)
  // [101711872, +402653184) R2: qkv (M x 576)  (bf16)
  // [504365056, +201326592) R3: h_buf (M x 192 f32, original token order)
  bf16* qkvw_h  = (bf16*)(ws);
  bf16* projw_h = (bf16*)(ws + 221184);
  bf16* fc1w_t  = (bf16*)(ws + 294912);
  bf16* fc2w_t  = (bf16*)(ws + 589824);
  bf16* r1      = (bf16*)(ws + (1L << 20));
  bf16* r2      = (bf16*)(ws + 101711872L);
  float* hbuf   = (float*)(ws + 504365056L);

  cvt_kernel<<<432, 256, 0, stream>>>(qkv_w, qkvw_h, 110592);
  cvt_kernel<<<144, 256, 0, stream>>>(proj_w, projw_h, 36864);
  cvt_frag_kernel<192, 6><<<576, 256, 0, stream>>>(fc1_w, fc1w_t, 147456);
  cvt_frag_kernel<768, 24><<<576, 256, 0, stream>>>(fc2_w, fc2w_t, 147456);

  // LN1 + roll + window partition -> zw (r1)
  ln_kernel<<<65536, 256, 0, stream>>>(x, n1_w, n1_b, r1);
  // QKV: zw @ qkv_w^T -> per-(window,head) Q|K|V blocks (r2)
  gemm_bt<0><<<dim3(3, 2048), 512, 0, stream>>>(r1, qkvw_h, qkv_b, 192, r2, nullptr, nullptr);
  // windowed attention -> attn_out (r1)
  attn_kernel<<<24576, 64, 0, stream>>>(r2, rpb, r1);
  // proj + window-reverse + roll + residual -> h_buf (r3, original order)
  gemm_bt<1><<<dim3(1, 2048), 512, 0, stream>>>(r1, projw_h, proj_b, 192, hbuf, x, nullptr);
  // fused LN2 + MLP: out = h + fc2(gelu(fc1(LN2(h))))
  mlp_fused<<<8192, 512, 0, stream>>>(hbuf, n2_w, n2_b, fc1w_t, fc1_b, fc2w_t, fc2_b,
                                      (float*)d_out);
}

// Round 15
// 804.419 us; speedup vs baseline: 1.1188x; 1.0188x over previous
//
#include <hip/hip_runtime.h>
#include <hip/hip_bf16.h>

typedef __attribute__((ext_vector_type(8))) __bf16 bf16x8;
typedef __attribute__((ext_vector_type(4))) float f32x4;
typedef __hip_bfloat16 bf16;

#define SCALE_Q 0.17677669529663687f

// global_load_lds: LDS dest linear (wave-uniform base + lane*16), source pre-swizzled per-lane.
#define LDSP(p) ((__attribute__((address_space(3))) unsigned int*)(unsigned long long)(p))
#define GPTR(p) ((const __attribute__((address_space(1))) unsigned int*)(unsigned long long)(p))
#define GLD16(gp, lp) __builtin_amdgcn_global_load_lds(GPTR(gp), LDSP(lp), 16, 0, 0)

// exact-grade GELU: Abramowitz-Stegun 7.1.26 erf (|err| < 1.5e-7)
__device__ inline float gelu_f(float x) {
  const float ax = fabsf(x) * 0.70710678118654752f;
  const float t = __builtin_amdgcn_rcpf(__builtin_fmaf(0.3275911f, ax, 1.0f));
  const float poly = t * __builtin_fmaf(t, __builtin_fmaf(t, __builtin_fmaf(t,
                     __builtin_fmaf(t, 1.061405429f, -1.453152027f),
                     1.421413741f), -0.284496736f), 0.254829592f);
  const float er = __builtin_fmaf(-poly, __expf(-ax * ax), 1.0f);
  return 0.5f * x * (1.0f + copysignf(er, x));
}

// ---------------- weight fp32 -> bf16 ----------------
__global__ void cvt_kernel(const float* __restrict__ in, bf16* __restrict__ out, int n) {
  int i = blockIdx.x * 256 + threadIdx.x;
  if (i < n) out[i] = __float2bfloat16(in[i]);
}

// ---- weight fp32 -> bf16 in MFMA B-fragment order ----
// src [N][K] row-major; dst chunk (n>>4, k>>5) holds [lg=(k>>3)&3][lr=n&15][e=k&7].
template<int K, int KC>
__global__ void cvt_frag_kernel(const float* __restrict__ in, bf16* __restrict__ out, int total) {
  int i = blockIdx.x * 256 + threadIdx.x;
  if (i < total) {
    const int n = i / K, k = i - n * K;
    out[((n >> 4) * KC + (k >> 5)) * 512 + ((k >> 3) & 3) * 128 + (n & 15) * 8 + (k & 7)] =
        __float2bfloat16(in[i]);
  }
}

// ---- LayerNorm1 fused with shifted-window gather, fp32 in -> bf16 out ----
__global__ __launch_bounds__(256) void ln_kernel(const float* __restrict__ in,
                                                 const float* __restrict__ gw,
                                                 const float* __restrict__ gb,
                                                 bf16* __restrict__ out) {
  const int t = blockIdx.x * 4 + (threadIdx.x >> 6);
  const int lane = threadIdx.x & 63;
  const int b_ = t >> 6, n = t & 63;
  const int b = b_ >> 10, wk = b_ & 1023, wi = wk >> 5, wj = wk & 31;
  const int i_ = n >> 3, j_ = n & 7;
  const int hf = (wi * 8 + i_ + 4) & 255, wf = (wj * 8 + j_ + 4) & 255;
  const long g = (((long)b * 256 + hf) * 256 + wf) * 192;
  const float x0 = in[g + lane], x1 = in[g + 64 + lane], x2 = in[g + 128 + lane];
  float s = x0 + x1 + x2;
  float s2 = x0 * x0 + x1 * x1 + x2 * x2;
  #pragma unroll
  for (int m = 1; m < 64; m <<= 1) { s += __shfl_xor(s, m); s2 += __shfl_xor(s2, m); }
  const float mu = s * (1.0f / 192.0f);
  const float rstd = rsqrtf(s2 * (1.0f / 192.0f) - mu * mu + 1e-5f);
  const long o = (long)t * 192;
  out[o + lane]       = __float2bfloat16((x0 - mu) * rstd * gw[lane]       + gb[lane]);
  out[o + 64 + lane]  = __float2bfloat16((x1 - mu) * rstd * gw[lane + 64]  + gb[lane + 64]);
  out[o + 128 + lane] = __float2bfloat16((x2 - mu) * rstd * gw[lane + 128] + gb[lane + 128]);
}

// ---------------- GEMM: C[m][n] = sum_k A[m][k] * W[n][k] (+bias), bf16 MFMA ----------------
// BM=128 BN=192 BK=64, 512 threads (8 waves, 4x2 grid, wave tile 32x96).
// EPI 0: qkv scatter (+q scale)   EPI 1: proj + window-reverse+roll + residual -> h_buf f32
template<int EPI>
__global__ __launch_bounds__(512, 4) void gemm_bt(const bf16* __restrict__ A,
                                                  const bf16* __restrict__ Bw,
                                                  const float* __restrict__ bias,
                                                  int K, void* __restrict__ outp,
                                                  const float* __restrict__ aux1,
                                                  const float* __restrict__ aux2) {
  __shared__ __align__(16) bf16 Ald[128 * 64];
  __shared__ __align__(16) bf16 Bld[192 * 64];
  const int tid = threadIdx.x;
  const int n0 = blockIdx.x * 192;
  const long m0 = (long)blockIdx.y * 128;
  const int lane = tid & 63, wid = tid >> 6;
  const int wr = (wid >> 1) * 32, wc = (wid & 1) * 96;
  const int lg = lane >> 4, lr = lane & 15;
  const int l3 = lane >> 3, l7 = lane & 7;
  const int chunk = l7 ^ l3;  // involutive source swizzle

  const bf16* aptr = A + (m0 + wid * 16 + l3) * (long)K + chunk * 8;
  const bf16* bptr = Bw + (n0 + wid * 24 + l3) * (long)K + chunk * 8;
  char* alds = (char*)Ald + wid * 16 * 128;
  char* blds = (char*)Bld + wid * 24 * 128;
  const long rk8 = 8 * (long)K;

  f32x4 acc[2][6];
  #pragma unroll
  for (int i = 0; i < 2; i++)
    #pragma unroll
    for (int j = 0; j < 6; j++) acc[i][j] = (f32x4){0.f, 0.f, 0.f, 0.f};

  for (int k0 = 0; k0 < K; k0 += 64) {
    GLD16(aptr + k0, alds);
    GLD16(aptr + rk8 + k0, alds + 1024);
    GLD16(bptr + k0, blds);
    GLD16(bptr + rk8 + k0, blds + 1024);
    GLD16(bptr + 2 * rk8 + k0, blds + 2048);
    __syncthreads();
    #pragma unroll
    for (int ks = 0; ks < 2; ks++) {
      bf16x8 af[2], bfr[6];
      #pragma unroll
      for (int i = 0; i < 2; i++) {
        const int row = wr + i * 16 + lr;
        af[i] = *(const bf16x8*)((const char*)Ald + row * 128 + (((ks * 4 + lg) ^ (row & 7)) * 16));
      }
      #pragma unroll
      for (int j = 0; j < 6; j++) {
        const int row = wc + j * 16 + lr;
        bfr[j] = *(const bf16x8*)((const char*)Bld + row * 128 + (((ks * 4 + lg) ^ (row & 7)) * 16));
      }
      #pragma unroll
      for (int i = 0; i < 2; i++)
        #pragma unroll
        for (int j = 0; j < 6; j++)
          acc[i][j] = __builtin_amdgcn_mfma_f32_16x16x32_bf16(af[i], bfr[j], acc[i][j], 0, 0, 0);
    }
    __syncthreads();
  }

  #pragma unroll
  for (int i = 0; i < 2; i++) {
    #pragma unroll
    for (int j = 0; j < 6; j++) {
      #pragma unroll
      for (int r = 0; r < 4; r++) {
        const long m = m0 + wr + i * 16 + lg * 4 + r;   // token row
        const int cn = n0 + wc + j * 16 + lr;           // output col
        float v = acc[i][j][r] + bias[cn];
        if (EPI == 0) {
          const long b_ = m >> 6; const int n = (int)(m & 63);
          const int which = cn / 192, rem = cn - which * 192, head = rem >> 5, d = rem & 31;
          if (which == 0) v *= SCALE_Q;
          ((bf16*)outp)[((b_ * 6 + head) * 3 + which) * 2048 + n * 32 + d] = __float2bfloat16(v);
        } else {
          const long b_ = m >> 6; const int n = (int)(m & 63);
          const int b = (int)(b_ >> 10), wk = (int)(b_ & 1023), wi = wk >> 5, wj = wk & 31;
          const int i_ = n >> 3, j_ = n & 7;
          const int hf = (wi * 8 + i_ + 4) & 255, wf = (wj * 8 + j_ + 4) & 255;
          const long g = (((long)b * 256 + hf) * 256 + wf) * 192 + cn;
          ((float*)outp)[g] = aux1[g] + v;   // h = shortcut + proj(attn)
        }
      }
    }
  }
}

// ------------ fused MLP v6: out = h + fc2(gelu(fc1(LN2(h)))) — BM=64 ------------
// = v5 structure scaled to BM=64 (512 thr, 120KB LDS -> 1 block/CU, 2 barriers).
// Halves per-chip L2 weight re-read traffic (7.2 -> 3.6 GB) and doubles MFMA per
// fragment load. Only 2 barriers, so 1 block/CU is tolerable (R8 lesson was about
// per-k-step barrier loops). All phase math identical to v5 -> bitwise-identical.
__global__ __launch_bounds__(512, 2) void mlp_fused(const float* __restrict__ hbuf,
                                                    const float* __restrict__ n2w,
                                                    const float* __restrict__ n2b,
                                                    const bf16* __restrict__ w1t,
                                                    const float* __restrict__ b1,
                                                    const bf16* __restrict__ w2t,
                                                    const float* __restrict__ b2,
                                                    float* __restrict__ outp) {
  __shared__ __align__(16) char smem[122880];
  char* Ab = smem;          // h_ln tile: 3 groups x [64 rows][8 slots][16B] = 24576
  char* G  = smem + 24576;  // g tile: [64 rows][96 slots][16B] = 98304

  const int tid = threadIdx.x;
  const long m0 = (long)blockIdx.x * 64;
  const int lane = tid & 63, wid = tid >> 6;
  const int lg = lane >> 4, lr = lane & 15;

  // ---- LN2: each wave normalizes 8 rows of hbuf -> Ab (swizzled bf16) ----
  #pragma unroll
  for (int t8 = 0; t8 < 8; t8++) {
    const int row = wid * 8 + t8;
    const long g = (m0 + row) * 192;
    const float x0 = hbuf[g + lane], x1 = hbuf[g + 64 + lane], x2 = hbuf[g + 128 + lane];
    float s = x0 + x1 + x2;
    float s2 = x0 * x0 + x1 * x1 + x2 * x2;
    #pragma unroll
    for (int msk = 1; msk < 64; msk <<= 1) { s += __shfl_xor(s, msk); s2 += __shfl_xor(s2, msk); }
    const float mu = s * (1.0f / 192.0f);
    const float rstd = rsqrtf(s2 * (1.0f / 192.0f) - mu * mu + 1e-5f);
    #pragma unroll
    for (int p = 0; p < 3; p++) {
      const int ch = p * 64 + lane;
      const float xv = (p == 0) ? x0 : (p == 1) ? x1 : x2;
      const float v = (xv - mu) * rstd * n2w[ch] + n2b[ch];
      const int c = (ch >> 3) & 7;               // chunk within 64-ch group
      const int slot = c ^ (row & 7);
      *(unsigned short*)(Ab + p * 8192 + row * 128 + slot * 16 + (ch & 7) * 2) =
          __builtin_bit_cast(unsigned short, __float2bfloat16(v));
    }
  }
  __syncthreads();

  // ---------------- fc1: barrier-free k-loop (A from LDS, w1t fragments from L2) ----------------
  f32x4 acc1[4][6];
  #pragma unroll
  for (int i = 0; i < 4; i++)
    #pragma unroll
    for (int j = 0; j < 6; j++) acc1[i][j] = (f32x4){0.f, 0.f, 0.f, 0.f};

  const int c16base = wid * 6;  // wave cols = wid*96 .. +96
  #pragma unroll
  for (int kc = 0; kc < 6; kc++) {
    const int q = kc >> 1;
    const int kk = (kc & 1) * 4 + lg;
    bf16x8 af[4], bfr[6];
    #pragma unroll
    for (int i = 0; i < 4; i++) {
      const int row = i * 16 + lr;
      af[i] = *(const bf16x8*)(Ab + q * 8192 + row * 128 + ((kk ^ (row & 7)) * 16));
    }
    #pragma unroll
    for (int j = 0; j < 6; j++)
      bfr[j] = *(const bf16x8*)(w1t + ((c16base + j) * 6 + kc) * 512 + lane * 8);
    #pragma unroll
    for (int i = 0; i < 4; i++)
      #pragma unroll
      for (int j = 0; j < 6; j++)
        acc1[i][j] = __builtin_amdgcn_mfma_f32_16x16x32_bf16(af[i], bfr[j], acc1[i][j], 0, 0, 0);
  }

  // gelu + write g tile to LDS (XOR-swizzled; proven v2/v3 code)
  #pragma unroll
  for (int j = 0; j < 6; j++) {
    const int n = wid * 96 + j * 16 + lr;
    const float bj = b1[n];
    const int c = n >> 3;
    #pragma unroll
    for (int i = 0; i < 4; i++) {
      #pragma unroll
      for (int r = 0; r < 4; r++) {
        const int m = i * 16 + lg * 4 + r;
        const int slot = (c & ~7) | ((c & 7) ^ (m & 7));
        *(unsigned short*)(G + m * 1536 + slot * 16 + (n & 7) * 2) =
            __builtin_bit_cast(unsigned short, __float2bfloat16(gelu_f(acc1[i][j][r] + bj)));
      }
    }
  }
  __syncthreads();

  // ---------------- fc2: v3's runtime k-loop (A from LDS g, w2t fragments from L2) ----------------
  const int wt = wid >> 2, wn = wid & 3;
  f32x4 acc2[2][3];
  #pragma unroll
  for (int i = 0; i < 2; i++)
    #pragma unroll
    for (int j = 0; j < 3; j++) acc2[i][j] = (f32x4){0.f, 0.f, 0.f, 0.f};

  for (int kt = 0; kt < 24; kt++) {
    const int c2 = kt * 4 + lg;  // global g chunk 0..95
    bf16x8 af2[2], bfr2[3];
    #pragma unroll
    for (int i = 0; i < 2; i++) {
      const int grow = wt * 32 + i * 16 + lr;
      const int slot2 = (c2 & ~7) | ((c2 & 7) ^ (grow & 7));
      af2[i] = *(const bf16x8*)(G + grow * 1536 + slot2 * 16);
    }
    #pragma unroll
    for (int j = 0; j < 3; j++)
      bfr2[j] = *(const bf16x8*)(w2t + ((wn * 3 + j) * 24 + kt) * 512 + lane * 8);
    #pragma unroll
    for (int i = 0; i < 2; i++)
      #pragma unroll
      for (int j = 0; j < 3; j++)
        acc2[i][j] = __builtin_amdgcn_mfma_f32_16x16x32_bf16(af2[i], bfr2[j], acc2[i][j], 0, 0, 0);
  }

  // epilogue: + bias + residual h -> out (f32)
  #pragma unroll
  for (int j = 0; j < 3; j++) {
    const int cn = wn * 48 + j * 16 + lr;
    const float bj = b2[cn];
    #pragma unroll
    for (int i = 0; i < 2; i++) {
      #pragma unroll
      for (int r = 0; r < 4; r++) {
        const long m = m0 + wt * 32 + i * 16 + lg * 4 + r;
        outp[m * 192 + cn] = acc2[i][j][r] + bj + hbuf[m * 192 + cn];
      }
    }
  }
}

// ---------------- windowed attention: one wave per (window, head) — proven round-1 ----------------
__global__ __launch_bounds__(64) void attn_kernel(const bf16* __restrict__ qkv,
                                                  const float* __restrict__ rpb,
                                                  bf16* __restrict__ outp) {
  __shared__ __align__(16) char smem[14848];
  __shared__ float rps[225];
  const int bid = blockIdx.x;
  const int b_ = bid / 6, head = bid - b_ * 6;
  const int lane = threadIdx.x;
  const long base = ((long)b_ * 6 + head) * 3 * 2048;

  for (int t = lane; t < 225; t += 64) rps[t] = rpb[t * 6 + head];

  #pragma unroll
  for (int q = 0; q < 4; q++) {
    const int f = q * 64 + lane, row = f >> 2, c = f & 3;
    *(uint4*)(smem + row * 80 + c * 16) = *(const uint4*)(qkv + base + row * 32 + c * 8);
    *(uint4*)(smem + 5120 + row * 80 + c * 16) = *(const uint4*)(qkv + base + 2048 + row * 32 + c * 8);
  }
  {  // stage V transposed: Vt[d][m]
    const bf16* vsrc = qkv + base + 4096 + lane * 32;
    bf16 vv[32];
    #pragma unroll
    for (int q = 0; q < 4; q++) *(uint4*)&vv[q * 8] = *(const uint4*)(vsrc + q * 8);
    bf16* vt = (bf16*)(smem + 10240);
    #pragma unroll
    for (int d = 0; d < 32; d++) vt[d * 72 + lane] = vv[d];
  }
  __syncthreads();

  const int lg = lane >> 4, lr = lane & 15;
  const f32x4 z4 = {0.f, 0.f, 0.f, 0.f};
  f32x4 s[4][4];
  {
    bf16x8 a[4], b[4];
    #pragma unroll
    for (int fi = 0; fi < 4; fi++)
      a[fi] = *(const bf16x8*)(smem + (fi * 16 + lr) * 80 + lg * 16);
    #pragma unroll
    for (int fj = 0; fj < 4; fj++)
      b[fj] = *(const bf16x8*)(smem + 5120 + (fj * 16 + lr) * 80 + lg * 16);
    #pragma unroll
    for (int fi = 0; fi < 4; fi++)
      #pragma unroll
      for (int fj = 0; fj < 4; fj++)
        s[fi][fj] = __builtin_amdgcn_mfma_f32_16x16x32_bf16(a[fi], b[fj], z4, 0, 0, 0);
  }

  const int wk = b_ & 1023; const int wi = wk >> 5, wj = wk & 31;
  const bool eh = (wi == 31), ew = (wj == 31);
  bf16* P = (bf16*)smem;
  #pragma unroll
  for (int fi = 0; fi < 4; fi++) {
    #pragma unroll
    for (int r = 0; r < 4; r++) {
      const int n = fi * 16 + lg * 4 + r;
      const int i1 = n >> 3, j1 = n & 7;
      const int labn = (eh ? (i1 < 4 ? 3 : 6) : 0) + (ew ? (j1 < 4 ? 1 : 2) : 0);
      float vals[4];
      #pragma unroll
      for (int fj = 0; fj < 4; fj++) {
        const int m = fj * 16 + lr;
        const int i2 = m >> 3, j2 = m & 7;
        const int labm = (eh ? (i2 < 4 ? 3 : 6) : 0) + (ew ? (j2 < 4 ? 1 : 2) : 0);
        vals[fj] = s[fi][fj][r] + rps[(i1 - i2 + 7) * 15 + (j1 - j2 + 7)]
                 + (labn != labm ? -100.0f : 0.0f);
      }
      float mx = fmaxf(fmaxf(vals[0], vals[1]), fmaxf(vals[2], vals[3]));
      #pragma unroll
      for (int msk = 1; msk < 16; msk <<= 1) mx = fmaxf(mx, __shfl_xor(mx, msk));
      float pe[4]; float sum = 0.f;
      #pragma unroll
      for (int fj = 0; fj < 4; fj++) { pe[fj] = __expf(vals[fj] - mx); sum += pe[fj]; }
      #pragma unroll
      for (int msk = 1; msk < 16; msk <<= 1) sum += __shfl_xor(sum, msk);
      const float rinv = 1.0f / sum;
      #pragma unroll
      for (int fj = 0; fj < 4; fj++)
        P[n * 72 + fj * 16 + lr] = __float2bfloat16(pe[fj] * rinv);
    }
  }
  __syncthreads();

  f32x4 o[4][2];
  #pragma unroll
  for (int fi = 0; fi < 4; fi++)
    #pragma unroll
    for (int fd = 0; fd < 2; fd++) o[fi][fd] = z4;
  const bf16* vt = (const bf16*)(smem + 10240);
  #pragma unroll
  for (int ks = 0; ks < 2; ks++) {
    bf16x8 pa[4], vb[2];
    #pragma unroll
    for (int fi = 0; fi < 4; fi++)
      pa[fi] = *(const bf16x8*)(P + (fi * 16 + lr) * 72 + ks * 32 + lg * 8);
    #pragma unroll
    for (int fd = 0; fd < 2; fd++)
      vb[fd] = *(const bf16x8*)(vt + (fd * 16 + lr) * 72 + ks * 32 + lg * 8);
    #pragma unroll
    for (int fi = 0; fi < 4; fi++)
      #pragma unroll
      for (int fd = 0; fd < 2; fd++)
        o[fi][fd] = __builtin_amdgcn_mfma_f32_16x16x32_bf16(pa[fi], vb[fd], o[fi][fd], 0, 0, 0);
  }
  #pragma unroll
  for (int fi = 0; fi < 4; fi++)
    #pragma unroll
    for (int fd = 0; fd < 2; fd++)
      #pragma unroll
      for (int r = 0; r < 4; r++) {
        const int n = fi * 16 + lg * 4 + r;
        outp[((long)b_ * 64 + n) * 192 + head * 32 + fd * 16 + lr] = __float2bfloat16(o[fi][fd][r]);
      }
}

extern "C" void kernel_launch(void* const* d_in, const int* in_sizes, int n_in,
                              void* d_out, int out_size, void* d_ws, size_t ws_size,
                              hipStream_t stream) {
  const float* x      = (const float*)d_in[0];
  const float* qkv_w  = (const float*)d_in[1];
  const float* qkv_b  = (const float*)d_in[2];
  const float* proj_w = (const float*)d_in[3];
  const float* proj_b = (const float*)d_in[4];
  const float* rpb    = (const float*)d_in[5];
  const float* n1_w   = (const float*)d_in[6];
  const float* n1_b   = (const float*)d_in[7];
  const float* n2_w   = (const float*)d_in[8];
  const float* n2_b   = (const float*)d_in[9];
  const float* fc1_w  = (const float*)d_in[10];
  const float* fc1_b  = (const float*)d_in[11];
  const float* fc2_w  = (const float*)d_in[12];
  const float* fc2_b  = (const float*)d_in[13];

  char* ws = (char*)d_ws;
  // workspace layout — round-1/5 proven layout (g + hln regions unused):
  // [0, 884736)             weights bf16 (fc1/fc2 in fragment order)
  // [1 MiB, +100663296)     R1: zw -> attn_out  (bf16, M x 192)
  // [101711872, +402653184) R2: qkv (M x 576)  (bf16)
  // [504365056, +201326592) R3: h_buf (M x 192 f32, original token order)
  bf16* qkvw_h  = (bf16*)(ws);
  bf16* projw_h = (bf16*)(ws + 221184);
  bf16* fc1w_t  = (bf16*)(ws + 294912);
  bf16* fc2w_t  = (bf16*)(ws + 589824);
  bf16* r1      = (bf16*)(ws + (1L << 20));
  bf16* r2      = (bf16*)(ws + 101711872L);
  float* hbuf   = (float*)(ws + 504365056L);

  cvt_kernel<<<432, 256, 0, stream>>>(qkv_w, qkvw_h, 110592);
  cvt_kernel<<<144, 256, 0, stream>>>(proj_w, projw_h, 36864);
  cvt_frag_kernel<192, 6><<<576, 256, 0, stream>>>(fc1_w, fc1w_t, 147456);
  cvt_frag_kernel<768, 24><<<576, 256, 0, stream>>>(fc2_w, fc2w_t, 147456);

  // LN1 + roll + window partition -> zw (r1)
  ln_kernel<<<65536, 256, 0, stream>>>(x, n1_w, n1_b, r1);
  // QKV: zw @ qkv_w^T -> per-(window,head) Q|K|V blocks (r2)
  gemm_bt<0><<<dim3(3, 2048), 512, 0, stream>>>(r1, qkvw_h, qkv_b, 192, r2, nullptr, nullptr);
  // windowed attention -> attn_out (r1)
  attn_kernel<<<24576, 64, 0, stream>>>(r2, rpb, r1);
  // proj + window-reverse + roll + residual -> h_buf (r3, original order)
  gemm_bt<1><<<dim3(1, 2048), 512, 0, stream>>>(r1, projw_h, proj_b, 192, hbuf, x, nullptr);
  // fused LN2 + MLP: out = h + fc2(gelu(fc1(LN2(h))))
  mlp_fused<<<4096, 512, 0, stream>>>(hbuf, n2_w, n2_b, fc1w_t, fc1_b, fc2w_t, fc2_b,
                                      (float*)d_out);
}